// Round 23
// baseline (1374.312 us; speedup 1.0000x reference)
//
#include <hip/hip_runtime.h>

#define TT 2048
#define BB 4
#define DD 512
#define HH 8
#define LL 8
#define FFD 2048
#define VV 256
#define ROWS (BB*TT)

typedef short bf16x4 __attribute__((ext_vector_type(4)));
typedef short bf16x8 __attribute__((ext_vector_type(8)));
typedef float f32x4 __attribute__((ext_vector_type(4)));

#define GL2LDS(gp, lp) __builtin_amdgcn_global_load_lds( \
    (const __attribute__((address_space(1))) unsigned*)(gp), \
    (__attribute__((address_space(3))) unsigned*)(lp), 16, 0, 0)

__device__ __forceinline__ float bf2f(short s){
  union { unsigned u; float f; } x; x.u = ((unsigned)(unsigned short)s) << 16; return x.f;
}
__device__ __forceinline__ short f2bf(float f){
  union { float f; unsigned u; } x; x.f = f;
  unsigned r = (x.u + 0x7fffu + ((x.u >> 16) & 1u)) >> 16;
  return (short)(unsigned short)r;
}
__device__ __forceinline__ float ex2(float x){
  float r; asm("v_exp_f32 %0, %1" : "=v"(r) : "v"(x)); return r;
}
__device__ __forceinline__ unsigned cvtpk(float lo, float hi){
  unsigned r; asm("v_cvt_pk_bf16_f32 %0, %1, %2" : "=v"(r) : "v"(lo), "v"(hi)); return r;
}
__device__ __forceinline__ float xmax32(float x){ return fmaxf(x, __shfl_xor(x, 32)); }
__device__ __forceinline__ float xadd32(float x){ return x + __shfl_xor(x, 32); }

// GELU via A&S 7.1.26 erf (|eps|<=1.5e-7), one v_exp
__device__ __forceinline__ float gelu_f(float v){
  float x = v * 0.70710678118f;
  float a = fabsf(x);
  float t = 1.0f / (1.0f + 0.3275911f * a);
  float poly = t*(0.254829592f + t*(-0.284496736f + t*(1.421413741f +
               t*(-1.453152027f + t*1.061405429f))));
  float er = 1.0f - poly * ex2(-1.44269504f * a * a);
  er = (x < 0.f) ? -er : er;
  return 0.5f * v * (1.0f + er);
}

// ---------------- embedding ----------------
__global__ __launch_bounds__(128) void embed_kernel(const int* __restrict__ x,
    const float* __restrict__ tok, const float* __restrict__ pos, float* __restrict__ h){
  int row = blockIdx.x;
  int t = row & (TT-1);
  int id = x[row];
  const float4 a = *(const float4*)&tok[(size_t)id*DD + threadIdx.x*4];
  const float4 p = *(const float4*)&pos[(size_t)t*DD + threadIdx.x*4];
  float4 r; r.x=a.x+p.x; r.y=a.y+p.y; r.z=a.z+p.z; r.w=a.w+p.w;
  *(float4*)&h[(size_t)row*DD + threadIdx.x*4] = r;
}

// ---------------- LayerNorm: one wave per row ----------------
__global__ __launch_bounds__(256) void ln_kernel(const float* __restrict__ xx,
    const float* __restrict__ gw, const float* __restrict__ bw, short* __restrict__ out){
  const int lane = threadIdx.x & 63, w = threadIdx.x >> 6;
  const int row = blockIdx.x*4 + w;
  const float* xp = xx + (size_t)row*DD + lane*8;
  float4 a = *(const float4*)xp, c = *(const float4*)(xp+4);
  float xv[8] = {a.x,a.y,a.z,a.w,c.x,c.y,c.z,c.w};
  float s1 = 0.f, s2 = 0.f;
  #pragma unroll
  for (int e=0;e<8;e++){ s1 += xv[e]; s2 += xv[e]*xv[e]; }
  #pragma unroll
  for (int off=1; off<64; off<<=1){
    s1 += __shfl_xor(s1, off);
    s2 += __shfl_xor(s2, off);
  }
  const float m = s1 * (1.0f/DD);
  const float rstd = rsqrtf(s2*(1.0f/DD) - m*m + 1e-5f);
  const float4 g0 = *(const float4*)(gw + lane*8), g1 = *(const float4*)(gw + lane*8 + 4);
  const float4 b0 = *(const float4*)(bw + lane*8), b1 = *(const float4*)(bw + lane*8 + 4);
  float gg[8] = {g0.x,g0.y,g0.z,g0.w,g1.x,g1.y,g1.z,g1.w};
  float bb[8] = {b0.x,b0.y,b0.z,b0.w,b1.x,b1.y,b1.z,b1.w};
  short r[8];
  #pragma unroll
  for (int e=0;e<8;e++) r[e] = f2bf((xv[e]-m)*rstd*gg[e] + bb[e]);
  *(bf16x8*)&out[(size_t)row*DD + lane*8] = *(const bf16x8*)r;
}

// ---------------- weight transpose+cast ----------------
__global__ __launch_bounds__(256) void transpose_cast_kernel(const float* __restrict__ src,
    short* __restrict__ dst, int R, int C){
  __shared__ float tile[32][33];
  size_t off = (size_t)blockIdx.z * R * C;
  src += off; dst += off;
  int c0 = blockIdx.x*32, r0 = blockIdx.y*32;
  int tx = threadIdx.x & 31, ty = threadIdx.x >> 5;
  #pragma unroll
  for (int i=0;i<4;i++) tile[ty + i*8][tx] = src[(size_t)(r0+ty+i*8)*C + c0 + tx];
  __syncthreads();
  #pragma unroll
  for (int i=0;i<4;i++) dst[(size_t)(c0+ty+i*8)*R + r0 + tx] = f2bf(tile[tx][ty+i*8]);
}

// ---------------- plain cast f32 -> bf16 ----------------
__global__ void cast_kernel(const float* __restrict__ in, short* __restrict__ out, int n){
  for (int i = blockIdx.x*blockDim.x + threadIdx.x; i < n; i += gridDim.x*blockDim.x)
    out[i] = f2bf(in[i]);
}

// row-band XCD swizzle: XCD x owns row-tiles [x*gx/8, ...) x all col-tiles.
__device__ __forceinline__ void xcd_rowband(int gx, int gy, int& rowt, int& colt){
  int lin = blockIdx.y*gx + blockIdx.x;
  int x = lin & 7, j = lin >> 3;
  int jd = j / gy;
  rowt = x*(gx >> 3) + jd;
  colt = j - jd*gy;
}

// ---------------- GEMM, 128x128 tile, 8 waves (wave = 64x32), BK=32 DBUF (32KB), counted vmcnt ----------------
// EPI: 1 = +bias -> bf16; 2 = +bias,GELU -> bf16
template<int EPI>
__global__ __launch_bounds__(512) void gemm_dma(const short* __restrict__ A,
    const short* __restrict__ BT, const float* __restrict__ bias, void* __restrict__ C,
    int M, int N, int K)
{
  __shared__ short As[2][128*32];
  __shared__ short Bs[2][128*32];
  int rowt, colt;
  xcd_rowband(gridDim.x, gridDim.y, rowt, colt);
  const int row0 = rowt*128, col0 = colt*128;
  const int t = threadIdx.x, lane = t & 63, w = t >> 6;
  const int wm = w >> 2, wn = w & 3;
  const int rr = lane & 15, g = lane >> 4;
  f32x4 acc[4][2];
  #pragma unroll
  for (int m=0;m<4;m++)
    #pragma unroll
    for (int n=0;n<2;n++) acc[m][n] = (f32x4){0.f,0.f,0.f,0.f};

  const int srow = lane >> 2;
  const short* aP = A  + (size_t)(row0 + w*16 + srow)*K + (lane&3)*8;
  const short* bP = BT + (size_t)(col0 + w*16 + srow)*K + (lane&3)*8;

  const int nk = K >> 5;
  GL2LDS(aP, &As[0][w*512]);
  GL2LDS(bP, &Bs[0][w*512]);
  if (nk > 1){
    GL2LDS(aP + 32, &As[1][w*512]);
    GL2LDS(bP + 32, &Bs[1][w*512]);
  }
  for (int kt=0; kt<nk; kt++){
    if (kt < nk-1) asm volatile("s_waitcnt vmcnt(2)\n\ts_barrier" ::: "memory");
    else           asm volatile("s_waitcnt vmcnt(0)\n\ts_barrier" ::: "memory");
    const short* Ac = As[kt&1];
    const short* Bc = Bs[kt&1];
    bf16x8 af[4], bfr[2];
    #pragma unroll
    for (int m=0;m<4;m++) af[m]  = *(const bf16x8*)&Ac[(wm*64 + m*16 + rr)*32 + g*8];
    #pragma unroll
    for (int n=0;n<2;n++) bfr[n] = *(const bf16x8*)&Bc[(wn*32 + n*16 + rr)*32 + g*8];
    __builtin_amdgcn_s_setprio(1);
    #pragma unroll
    for (int m=0;m<4;m++)
      #pragma unroll
      for (int n=0;n<2;n++)
        acc[m][n] = __builtin_amdgcn_mfma_f32_16x16x32_bf16(af[m], bfr[n], acc[m][n], 0,0,0);
    __builtin_amdgcn_s_setprio(0);
    if (kt+2 < nk){
      asm volatile("s_waitcnt lgkmcnt(0)\n\ts_barrier" ::: "memory");
      const int ko = (kt+2) << 5;
      GL2LDS(aP + ko, &As[kt&1][w*512]);
      GL2LDS(bP + ko, &Bs[kt&1][w*512]);
    }
  }
  #pragma unroll
  for (int m=0;m<4;m++){
    #pragma unroll
    for (int n=0;n<2;n++){
      int cg = col0 + wn*32 + n*16 + rr;
      float bv = bias[cg];
      #pragma unroll
      for (int i=0;i<4;i++){
        int rg = row0 + wm*64 + m*16 + g*4 + i;
        float v = acc[m][n][i] + bv;
        size_t idx = (size_t)rg*N + cg;
        if constexpr (EPI==1) ((short*)C)[idx] = f2bf(v);
        else ((short*)C)[idx] = f2bf(gelu_f(v));
      }
    }
  }
}

// ---------------- GEMM, 256x128 tile, 8 waves (wave = 64x64, acc 4x4), BK=32 ring-of-3 ----------------
template<int EPI>
__global__ __launch_bounds__(512) void gemm_dma_256(const short* __restrict__ A,
    const short* __restrict__ BT, const float* __restrict__ bias, void* __restrict__ C,
    int M, int N, int K)
{
  __shared__ short As[3][256*32];   // 48 KB
  __shared__ short Bs[3][128*32];   // 24 KB
  int rowt, colt;
  xcd_rowband(gridDim.x, gridDim.y, rowt, colt);
  const int row0 = rowt*256, col0 = colt*128;
  const int t = threadIdx.x, lane = t & 63, w = t >> 6;
  const int wm = w >> 1, wn = w & 1;
  const int rr = lane & 15, g = lane >> 4;
  f32x4 acc[4][4];
  #pragma unroll
  for (int m=0;m<4;m++)
    #pragma unroll
    for (int n=0;n<4;n++) acc[m][n] = (f32x4){0.f,0.f,0.f,0.f};

  const int srow = lane >> 2;
  const short* aP = A  + (size_t)(row0 + w*32 + srow)*K + (lane&3)*8;
  const short* bP = BT + (size_t)(col0 + w*16 + srow)*K + (lane&3)*8;

  const int nk = K >> 5;
  #pragma unroll
  for (int i=0;i<2;i++) GL2LDS(aP + (size_t)i*16*K, &As[0][w*1024 + i*512]);
  GL2LDS(bP, &Bs[0][w*512]);
  if (nk > 1){
    #pragma unroll
    for (int i=0;i<2;i++) GL2LDS(aP + (size_t)i*16*K + 32, &As[1][w*1024 + i*512]);
    GL2LDS(bP + 32, &Bs[1][w*512]);
  }
  int cur = 0, st = 2;
  for (int kt=0; kt<nk; kt++){
    if (kt < nk-1) asm volatile("s_waitcnt vmcnt(3) lgkmcnt(0)\n\ts_barrier" ::: "memory");
    else           asm volatile("s_waitcnt vmcnt(0) lgkmcnt(0)\n\ts_barrier" ::: "memory");
    if (kt+2 < nk){
      const int ko = (kt+2) << 5;
      #pragma unroll
      for (int i=0;i<2;i++) GL2LDS(aP + (size_t)i*16*K + ko, &As[st][w*1024 + i*512]);
      GL2LDS(bP + ko, &Bs[st][w*512]);
    }
    const short* Ac = As[cur];
    const short* Bc = Bs[cur];
    bf16x8 af[4], bfr[4];
    #pragma unroll
    for (int m=0;m<4;m++) af[m]  = *(const bf16x8*)&Ac[(wm*64 + m*16 + rr)*32 + g*8];
    #pragma unroll
    for (int n=0;n<4;n++) bfr[n] = *(const bf16x8*)&Bc[(wn*64 + n*16 + rr)*32 + g*8];
    __builtin_amdgcn_s_setprio(1);
    #pragma unroll
    for (int m=0;m<4;m++)
      #pragma unroll
      for (int n=0;n<4;n++)
        acc[m][n] = __builtin_amdgcn_mfma_f32_16x16x32_bf16(af[m], bfr[n], acc[m][n], 0,0,0);
    __builtin_amdgcn_s_setprio(0);
    cur = (cur==2) ? 0 : cur+1;
    st  = (st==2)  ? 0 : st+1;
  }
  #pragma unroll
  for (int m=0;m<4;m++){
    #pragma unroll
    for (int n=0;n<4;n++){
      int cg = col0 + wn*64 + n*16 + rr;
      float bv = bias[cg];
      #pragma unroll
      for (int i=0;i<4;i++){
        int rg = row0 + wm*64 + m*16 + g*4 + i;
        float v = acc[m][n][i] + bv;
        size_t idx = (size_t)rg*N + cg;
        if constexpr (EPI==1) ((short*)C)[idx] = f2bf(v);
        else ((short*)C)[idx] = f2bf(gelu_f(v));
      }
    }
  }
}

// ---------------- GEMM 128x64 tile, 8 waves (wave = 32x32), BK=32 ring-of-3, residual += ----------------
__global__ __launch_bounds__(512) void gemm_dma_n64(const short* __restrict__ A,
    const short* __restrict__ BT, const float* __restrict__ bias, float* __restrict__ C,
    int M, int N, int K)
{
  __shared__ short As[3][128*32];
  __shared__ short Bs[3][64*32];
  int rowt, colt;
  xcd_rowband(gridDim.x, gridDim.y, rowt, colt);
  const int row0 = rowt*128, col0 = colt*64;
  const int t = threadIdx.x, lane = t & 63, w = t >> 6;
  const int wm = w >> 1, wn = w & 1;
  const int rr = lane & 15, g = lane >> 4;
  f32x4 acc[2][2];
  #pragma unroll
  for (int m=0;m<2;m++)
    #pragma unroll
    for (int n=0;n<2;n++) acc[m][n] = (f32x4){0.f,0.f,0.f,0.f};

  const int srow = lane >> 2;
  const short* aP = A  + (size_t)(row0 + w*16 + srow)*K + (lane&3)*8;
  const short* bP = BT + (size_t)(col0 + (w&3)*16 + srow)*K + (lane&3)*8;

  const int nk = K >> 5;
  GL2LDS(aP, &As[0][w*512]);
  if (w < 4) GL2LDS(bP, &Bs[0][w*512]);
  if (nk > 1){
    GL2LDS(aP + 32, &As[1][w*512]);
    if (w < 4) GL2LDS(bP + 32, &Bs[1][w*512]);
  }
  int cur = 0, st = 2;
  for (int kt=0; kt<nk; kt++){
    if (kt < nk-1){
      if (w < 4) asm volatile("s_waitcnt vmcnt(2) lgkmcnt(0)\n\ts_barrier" ::: "memory");
      else       asm volatile("s_waitcnt vmcnt(1) lgkmcnt(0)\n\ts_barrier" ::: "memory");
    } else       asm volatile("s_waitcnt vmcnt(0) lgkmcnt(0)\n\ts_barrier" ::: "memory");
    if (kt+2 < nk){
      const int ko = (kt+2) << 5;
      GL2LDS(aP + ko, &As[st][w*512]);
      if (w < 4) GL2LDS(bP + ko, &Bs[st][w*512]);
    }
    const short* Ac = As[cur];
    const short* Bc = Bs[cur];
    bf16x8 af[2], bfr[2];
    #pragma unroll
    for (int m=0;m<2;m++) af[m]  = *(const bf16x8*)&Ac[(wm*32 + m*16 + rr)*32 + g*8];
    #pragma unroll
    for (int n=0;n<2;n++) bfr[n] = *(const bf16x8*)&Bc[(wn*32 + n*16 + rr)*32 + g*8];
    __builtin_amdgcn_s_setprio(1);
    #pragma unroll
    for (int m=0;m<2;m++)
      #pragma unroll
      for (int n=0;n<2;n++)
        acc[m][n] = __builtin_amdgcn_mfma_f32_16x16x32_bf16(af[m], bfr[n], acc[m][n], 0,0,0);
    __builtin_amdgcn_s_setprio(0);
    cur = (cur==2) ? 0 : cur+1;
    st  = (st==2)  ? 0 : st+1;
  }
  #pragma unroll
  for (int m=0;m<2;m++){
    #pragma unroll
    for (int n=0;n<2;n++){
      int cg = col0 + wn*32 + n*16 + rr;
      float bv = bias[cg];
      #pragma unroll
      for (int i=0;i<4;i++){
        int rg = row0 + wm*32 + m*16 + g*4 + i;
        C[(size_t)rg*N + cg] += acc[m][n][i] + bv;
      }
    }
  }
}

// ---------------- small reg-staged GEMM (lm_head) ----------------
template<int BM, int BN>
__global__ __launch_bounds__(256) void gemm_small(const short* __restrict__ A,
    const short* __restrict__ BT, float* __restrict__ C, int M, int N, int K)
{
  constexpr int FM = BM/32, FN = BN/32;
  __shared__ short As[BM][72];
  __shared__ short Bs[BN][72];
  const int row0 = blockIdx.x*BM, col0 = blockIdx.y*BN;
  const int t = threadIdx.x, lane = t & 63, w = t >> 6;
  const int wm = w >> 1, wn = w & 1;
  const int rr = lane & 15, kg = (lane >> 4)*8;
  f32x4 acc[FM][FN];
  #pragma unroll
  for (int m=0;m<FM;m++)
    #pragma unroll
    for (int n=0;n<FN;n++) acc[m][n] = (f32x4){0.f,0.f,0.f,0.f};

  for (int kt=0; kt<K; kt+=64){
    #pragma unroll
    for (int i=0;i<BM/32;i++){
      int cid = t + i*256; int r = cid >> 3; int c = (cid & 7)*8;
      *(bf16x8*)&As[r][c] = *(const bf16x8*)&A[(size_t)(row0+r)*K + kt + c];
    }
    #pragma unroll
    for (int i=0;i<BN/32;i++){
      int cid = t + i*256; int r = cid >> 3; int c = (cid & 7)*8;
      *(bf16x8*)&Bs[r][c] = *(const bf16x8*)&BT[(size_t)(col0+r)*K + kt + c];
    }
    __syncthreads();
    #pragma unroll
    for (int ks=0; ks<2; ks++){
      bf16x8 af[FM], bfr[FN];
      #pragma unroll
      for (int m=0;m<FM;m++) af[m] = *(const bf16x8*)&As[wm*FM*16 + m*16 + rr][ks*32 + kg];
      #pragma unroll
      for (int n=0;n<FN;n++) bfr[n] = *(const bf16x8*)&Bs[wn*FN*16 + n*16 + rr][ks*32 + kg];
      #pragma unroll
      for (int m=0;m<FM;m++)
        #pragma unroll
        for (int n=0;n<FN;n++)
          acc[m][n] = __builtin_amdgcn_mfma_f32_16x16x32_bf16(af[m], bfr[n], acc[m][n], 0,0,0);
    }
    __syncthreads();
  }
  #pragma unroll
  for (int m=0;m<FM;m++)
    #pragma unroll
    for (int n=0;n<FN;n++){
      int cg = col0 + wn*FN*16 + n*16 + rr;
      #pragma unroll
      for (int i=0;i<4;i++){
        int rg = row0 + wm*FM*16 + m*16 + (lane>>4)*4 + i;
        C[(size_t)rg*N + cg] = acc[m][n][i];
      }
    }
}

// ---------------- attention: per-tile compute for one q-state ----------------
__device__ __forceinline__ void attn_tile(const short* __restrict__ Kc,
    const short* __restrict__ Vc, const bf16x8* qr, f32x4* oacc,
    float& mrun, float& lpart, int qi, int g, int qloc, bool diag)
{
  f32x4 sacc[4];
  #pragma unroll
  for (int f=0; f<4; f++) sacc[f] = (f32x4){0.f,0.f,0.f,0.f};
  __builtin_amdgcn_s_setprio(1);
  #pragma unroll
  for (int ks=0; ks<2; ks++){
    #pragma unroll
    for (int f=0; f<4; f++){
      bf16x8 kf = *(const bf16x8*)&Kc[(f*16 + qi)*64 + (((ks*4 + g) ^ (qi&7))*8)];
      sacc[f] = __builtin_amdgcn_mfma_f32_16x16x32_bf16(kf, qr[ks], sacc[f], 0,0,0);
    }
  }
  __builtin_amdgcn_s_setprio(0);

  float p[4][4];
  if (diag){
    #pragma unroll
    for (int f=0; f<4; f++)
      #pragma unroll
      for (int i=0; i<4; i++){
        int koffs = f*16 + g*4 + i;
        p[f][i] = (koffs <= qloc) ? sacc[f][i] : -1e30f;
      }
  } else {
    #pragma unroll
    for (int f=0; f<4; f++)
      #pragma unroll
      for (int i=0; i<4; i++) p[f][i] = sacc[f][i];
  }
  float t0 = fmaxf(fmaxf(p[0][0],p[0][1]), fmaxf(p[0][2],p[0][3]));
  float t1 = fmaxf(fmaxf(p[1][0],p[1][1]), fmaxf(p[1][2],p[1][3]));
  float t2 = fmaxf(fmaxf(p[2][0],p[2][1]), fmaxf(p[2][2],p[2][3]));
  float t3 = fmaxf(fmaxf(p[3][0],p[3][1]), fmaxf(p[3][2],p[3][3]));
  float tm = fmaxf(fmaxf(t0,t1), fmaxf(t2,t3));
  tm = fmaxf(tm, __shfl_xor(tm, 16));
  tm = xmax32(tm);
  if (!__all(tm <= mrun + 8.f)){            // defer-max (log2 units)
    float mnew = fmaxf(mrun, tm);
    float corr = ex2(mrun - mnew);
    lpart *= corr;
    #pragma unroll
    for (int mf=0; mf<4; mf++)
      #pragma unroll
      for (int i=0; i<4; i++) oacc[mf][i] *= corr;
    mrun = mnew;
  }
  float ts = 0.f;
  #pragma unroll
  for (int f=0; f<4; f++)
    #pragma unroll
    for (int i=0; i<4; i++){
      float e = ex2(p[f][i] - mrun);
      p[f][i] = e;
      ts += e;
    }
  lpart += ts;

  __builtin_amdgcn_s_setprio(1);
  #pragma unroll
  for (int w2=0; w2<2; w2++){
    union { unsigned u[4]; bf16x8 v; } bfr;
    bfr.u[0] = cvtpk(p[2*w2  ][0], p[2*w2  ][1]);
    bfr.u[1] = cvtpk(p[2*w2  ][2], p[2*w2  ][3]);
    bfr.u[2] = cvtpk(p[2*w2+1][0], p[2*w2+1][1]);
    bfr.u[3] = cvtpk(p[2*w2+1][2], p[2*w2+1][3]);
    #pragma unroll
    for (int mf=0; mf<4; mf++){
      const short* vp = &Vc[(mf*16 + qi)*72 + w2*32 + g*4];
      union { bf16x4 h[2]; bf16x8 v; } af;
      af.h[0] = *(const bf16x4*)vp;
      af.h[1] = *(const bf16x4*)(vp + 16);
      oacc[mf] = __builtin_amdgcn_mfma_f32_16x16x32_bf16(af.v, bfr.v, oacc[mf], 0,0,0);
    }
  }
  __builtin_amdgcn_s_setprio(0);
}

// ---------------- MFMA flash attention v9: counted-vmcnt ring (K ring-of-3, V 3-deep regs) ----------------
// 512 blocks, 8 waves. K-DMA and V-loads get 2 compute-phases of cover; barriers use
// vmcnt(2) in steady state (drain-0 only at the tail).
__global__ __launch_bounds__(512) void attn_kernel(const short* __restrict__ qkv, short* __restrict__ o){
  __shared__ __align__(16) char smem[43008];
  short* KsB = (short*)smem;             // 3 x [64][64], chunk-swizzled
  short* VtB = (short*)(smem + 24576);   // 2 x Vt[d][k] [64][72]
  float* Osh = (float*)smem;             // [128][65] alias (epilogue only)

  const int lin = blockIdx.x;
  const int xcd = lin & 7, idx = lin >> 3;
  const int bh = xcd*4 + (idx & 3);
  const int j = 15 - (idx >> 2);
  const int q0 = j*128;
  const int nt = 2*j + 2;
  const int b = bh >> 3, hh = bh & 7;

  const int t = threadIdx.x, lane = t & 63, wid = t >> 6;
  const int g = lane >> 4, qi = lane & 15;
  const int qg = q0 + wid*16 + qi;
  const int myqt = 2*j + (wid >> 2);
  const int qrel = ((wid & 3) << 4) + qi;
  const size_t base = (size_t)b*TT*3*DD + hh*64;

  bf16x8 qreg[2];
  {
    const float qs = 0.125f * 1.44269504f;
    const short* qp = qkv + base + (size_t)qg*3*DD + g*8;
    qreg[0] = *(const bf16x8*)&qp[0];
    qreg[1] = *(const bf16x8*)&qp[32];
    #pragma unroll
    for (int jj=0;jj<8;jj++){
      qreg[0][jj] = f2bf(qs * bf2f(qreg[0][jj]));
      qreg[1][jj] = f2bf(qs * bf2f(qreg[1][jj]));
    }
  }
  f32x4 oacc[4];
  #pragma unroll
  for (int mf=0; mf<4; mf++) oacc[mf] = (f32x4){0.f,0.f,0.f,0.f};
  float mrun = -1e30f, lrun = 0.f;

  const int kw = wid & 3;
  const short* ksrc = qkv + base + DD + (size_t)(kw*16 + (lane>>3))*3*DD
                      + (((lane&7) ^ (lane>>3))*8);
  const int vk = (t & 31)*2, vd = ((t >> 5) & 7)*8;
  const short* vsrc = qkv + base + 2*DD + (size_t)vk*3*DD + vd;

  // V 3-deep register pipeline: vW (write-ready), vF1, vF2 (in flight)
  bf16x8 vWa{}, vWb{}, vF1a{}, vF1b{}, vF2a{}, vF2b{};

  // ---- prologue ----
  if (wid >= 4){
    // K(0) -> buf0, K(1) -> buf1  (4 loads in flight)
    GL2LDS(ksrc, KsB + kw*1024);
    GL2LDS(ksrc + (size_t)8*3*DD, KsB + kw*1024 + 512);
    GL2LDS(ksrc + (size_t)64*3*DD, KsB + 4096 + kw*1024);
    GL2LDS(ksrc + (size_t)64*3*DD + (size_t)8*3*DD, KsB + 4096 + kw*1024 + 512);
  } else {
    bf16x8 t0a = *(const bf16x8*)vsrc;                       // V(0)
    bf16x8 t0b = *(const bf16x8*)(vsrc + 3*DD);
    vWa = *(const bf16x8*)(vsrc + (size_t)64*3*DD);          // V(1)
    vWb = *(const bf16x8*)(vsrc + (size_t)64*3*DD + 3*DD);
    if (nt > 2){
      vF1a = *(const bf16x8*)(vsrc + (size_t)128*3*DD);      // V(2)
      vF1b = *(const bf16x8*)(vsrc + (size_t)128*3*DD + 3*DD);
      asm volatile("s_waitcnt vmcnt(4)" ::: "memory");       // V(0) ready
    } else {
      asm volatile("s_waitcnt vmcnt(2)" ::: "memory");
    }
    #pragma unroll
    for (int e=0;e<8;e++)
      *(unsigned*)&VtB[(vd+e)*72 + vk] =
          (unsigned)(unsigned short)t0a[e] | ((unsigned)(unsigned short)t0b[e] << 16);
  }

  int kcur = 0;
  for (int kb = 0; kb < nt; kb++){
    // steady state: 4 loads outstanding per wave; vmcnt(2) drains the pair needed now.
    if (kb+2 < nt) asm volatile("s_waitcnt vmcnt(2) lgkmcnt(0)\n\ts_barrier" ::: "memory");
    else           asm volatile("s_waitcnt vmcnt(0) lgkmcnt(0)\n\ts_barrier" ::: "memory");
    if (wid >= 4){
      if (kb+2 < nt){
        int bst = kcur + 2; if (bst >= 3) bst -= 3;          // (kb+2)%3
        const size_t koff = (size_t)(kb+2)*64*3*DD;
        GL2LDS(ksrc + koff, KsB + bst*4096 + kw*1024);
        GL2LDS(ksrc + koff + (size_t)8*3*DD, KsB + bst*4096 + kw*1024 + 512);
      }
    } else {
      if (kb+1 < nt){
        short* Vn = VtB + ((kb+1)&1)*4608;
        #pragma unroll
        for (int e=0;e<8;e++)
          *(unsigned*)&Vn[(vd+e)*72 + vk] =
              (unsigned)(unsigned short)vWa[e] | ((unsigned)(unsigned short)vWb[e] << 16);
      }
      if (kb+3 < nt){
        const size_t koff3 = (size_t)(kb+3)*64*3*DD;
        vF2a = *(const bf16x8*)(vsrc + koff3);
        vF2b = *(const bf16x8*)(vsrc + koff3 + 3*DD);
      }
    }
    const short* Kc = KsB + kcur*4096;
    const short* Vc = VtB + (kb&1)*4608;

    if (kb <= myqt)
      attn_tile(Kc, Vc, qreg, oacc, mrun, lrun, qi, g, qrel, kb == myqt);

    // rotate V pipeline (static register moves)
    vWa = vF1a; vWb = vF1b;
    vF1a = vF2a; vF1b = vF2b;
    kcur = (kcur == 2) ? 0 : kcur + 1;
  }

  lrun += __shfl_xor(lrun, 16);
  lrun = xadd32(lrun);

  __syncthreads();
  const float inv = 1.f / lrun;
  const int qloc128 = wid*16 + qi;
  #pragma unroll
  for (int mf=0; mf<4; mf++)
    #pragma unroll
    for (int i=0; i<4; i++)
      Osh[qloc128*65 + mf*16 + g*4 + i] = oacc[mf][i] * inv;
  __syncthreads();
  {
    const int orow = t >> 2, cc = (t & 3) * 16;
    short tmp[16];
    #pragma unroll
    for (int e=0; e<16; e++) tmp[e] = f2bf(Osh[orow*65 + cc + e]);
    short* op = o + ((size_t)b*TT + q0 + orow)*DD + hh*64 + cc;
    *(bf16x8*)&op[0] = *(const bf16x8*)&tmp[0];
    *(bf16x8*)&op[8] = *(const bf16x8*)&tmp[8];
  }
}

extern "C" void kernel_launch(void* const* d_in, const int* in_sizes, int n_in,
                              void* d_out, int out_size, void* d_ws, size_t ws_size,
                              hipStream_t stream) {
  const int*   x      = (const int*)d_in[0];
  const float* tok    = (const float*)d_in[1];
  const float* pos    = (const float*)d_in[2];
  const float* attn_w = (const float*)d_in[3];
  const float* attn_b = (const float*)d_in[4];
  const float* proj_w = (const float*)d_in[5];
  const float* proj_b = (const float*)d_in[6];
  const float* ln1_g  = (const float*)d_in[7];
  const float* ln1_b  = (const float*)d_in[8];
  const float* ln2_g  = (const float*)d_in[9];
  const float* ln2_b  = (const float*)d_in[10];
  const float* ff1_w  = (const float*)d_in[11];
  const float* ff1_b  = (const float*)d_in[12];
  const float* ff2_w  = (const float*)d_in[13];
  const float* ff2_b  = (const float*)d_in[14];
  const float* lnf_g  = (const float*)d_in[15];
  const float* lnf_b  = (const float*)d_in[16];

  char* p = (char*)d_ws;
  float* h   = (float*)p; p += (size_t)ROWS*DD*4;
  short* hn  = (short*)p; p += (size_t)ROWS*DD*2;
  short* qkv = (short*)p; p += (size_t)ROWS*3*DD*2;
  short* ob  = (short*)p; p += (size_t)ROWS*DD*2;
  short* ffb = (short*)p; p += (size_t)ROWS*FFD*2;
  short* awT = (short*)p; p += (size_t)LL*3*DD*DD*2;
  short* pwT = (short*)p; p += (size_t)LL*DD*DD*2;
  short* f1T = (short*)p; p += (size_t)LL*FFD*DD*2;
  short* f2T = (short*)p; p += (size_t)LL*DD*FFD*2;
  short* lmT = (short*)p; p += (size_t)VV*DD*2;

  transpose_cast_kernel<<<dim3(48,16,8),256,0,stream>>>(attn_w, awT, DD, 3*DD);
  transpose_cast_kernel<<<dim3(16,16,8),256,0,stream>>>(proj_w, pwT, DD, DD);
  transpose_cast_kernel<<<dim3(64,16,8),256,0,stream>>>(ff1_w, f1T, DD, FFD);
  transpose_cast_kernel<<<dim3(16,64,8),256,0,stream>>>(ff2_w, f2T, FFD, DD);
  cast_kernel<<<128,256,0,stream>>>(tok, lmT, VV*DD);
  embed_kernel<<<ROWS,128,0,stream>>>(x, tok, pos, h);

  for (int l=0;l<LL;l++){
    ln_kernel<<<ROWS/4,256,0,stream>>>(h, ln1_g + l*DD, ln1_b + l*DD, hn);
    gemm_dma<1><<<dim3(ROWS/128, (3*DD)/128),512,0,stream>>>(
        hn, awT + (size_t)l*3*DD*DD, attn_b + (size_t)l*3*DD, qkv, ROWS, 3*DD, DD);
    attn_kernel<<<512,512,0,stream>>>(qkv, ob);
    gemm_dma_n64<<<dim3(ROWS/128, DD/64),512,0,stream>>>(
        ob, pwT + (size_t)l*DD*DD, proj_b + (size_t)l*DD, h, ROWS, DD, DD);
    ln_kernel<<<ROWS/4,256,0,stream>>>(h, ln2_g + l*DD, ln2_b + l*DD, hn);
    gemm_dma_256<2><<<dim3(ROWS/256, FFD/128),512,0,stream>>>(
        hn, f1T + (size_t)l*FFD*DD, ff1_b + (size_t)l*FFD, ffb, ROWS, FFD, DD);
    gemm_dma_n64<<<dim3(ROWS/128, DD/64),512,0,stream>>>(
        ffb, f2T + (size_t)l*DD*FFD, ff2_b + (size_t)l*DD, h, ROWS, DD, FFD);
  }
  ln_kernel<<<ROWS/4,256,0,stream>>>(h, lnf_g, lnf_b, hn);
  gemm_small<64,64><<<dim3(ROWS/64, VV/64),256,0,stream>>>(
      hn, lmT, (float*)d_out, ROWS, VV, DD);
}

// Round 24
// 1367.534 us; speedup vs baseline: 1.0050x; 1.0050x over previous
//
#include <hip/hip_runtime.h>

#define TT 2048
#define BB 4
#define DD 512
#define HH 8
#define LL 8
#define FFD 2048
#define VV 256
#define ROWS (BB*TT)

typedef short bf16x4 __attribute__((ext_vector_type(4)));
typedef short bf16x8 __attribute__((ext_vector_type(8)));
typedef float f32x4 __attribute__((ext_vector_type(4)));

#define GL2LDS(gp, lp) __builtin_amdgcn_global_load_lds( \
    (const __attribute__((address_space(1))) unsigned*)(gp), \
    (__attribute__((address_space(3))) unsigned*)(lp), 16, 0, 0)

__device__ __forceinline__ float bf2f(short s){
  union { unsigned u; float f; } x; x.u = ((unsigned)(unsigned short)s) << 16; return x.f;
}
__device__ __forceinline__ short f2bf(float f){
  union { float f; unsigned u; } x; x.f = f;
  unsigned r = (x.u + 0x7fffu + ((x.u >> 16) & 1u)) >> 16;
  return (short)(unsigned short)r;
}
__device__ __forceinline__ float ex2(float x){
  float r; asm("v_exp_f32 %0, %1" : "=v"(r) : "v"(x)); return r;
}
__device__ __forceinline__ unsigned cvtpk(float lo, float hi){
  unsigned r; asm("v_cvt_pk_bf16_f32 %0, %1, %2" : "=v"(r) : "v"(lo), "v"(hi)); return r;
}
__device__ __forceinline__ float xmax32(float x){ return fmaxf(x, __shfl_xor(x, 32)); }
__device__ __forceinline__ float xadd32(float x){ return x + __shfl_xor(x, 32); }

// GELU via A&S 7.1.26 erf (|eps|<=1.5e-7), one v_exp
__device__ __forceinline__ float gelu_f(float v){
  float x = v * 0.70710678118f;
  float a = fabsf(x);
  float t = 1.0f / (1.0f + 0.3275911f * a);
  float poly = t*(0.254829592f + t*(-0.284496736f + t*(1.421413741f +
               t*(-1.453152027f + t*1.061405429f))));
  float er = 1.0f - poly * ex2(-1.44269504f * a * a);
  er = (x < 0.f) ? -er : er;
  return 0.5f * v * (1.0f + er);
}

// ---------------- embedding ----------------
__global__ __launch_bounds__(128) void embed_kernel(const int* __restrict__ x,
    const float* __restrict__ tok, const float* __restrict__ pos, float* __restrict__ h){
  int row = blockIdx.x;
  int t = row & (TT-1);
  int id = x[row];
  const float4 a = *(const float4*)&tok[(size_t)id*DD + threadIdx.x*4];
  const float4 p = *(const float4*)&pos[(size_t)t*DD + threadIdx.x*4];
  float4 r; r.x=a.x+p.x; r.y=a.y+p.y; r.z=a.z+p.z; r.w=a.w+p.w;
  *(float4*)&h[(size_t)row*DD + threadIdx.x*4] = r;
}

// ---------------- LayerNorm: one wave per row ----------------
__global__ __launch_bounds__(256) void ln_kernel(const float* __restrict__ xx,
    const float* __restrict__ gw, const float* __restrict__ bw, short* __restrict__ out){
  const int lane = threadIdx.x & 63, w = threadIdx.x >> 6;
  const int row = blockIdx.x*4 + w;
  const float* xp = xx + (size_t)row*DD + lane*8;
  float4 a = *(const float4*)xp, c = *(const float4*)(xp+4);
  float xv[8] = {a.x,a.y,a.z,a.w,c.x,c.y,c.z,c.w};
  float s1 = 0.f, s2 = 0.f;
  #pragma unroll
  for (int e=0;e<8;e++){ s1 += xv[e]; s2 += xv[e]*xv[e]; }
  #pragma unroll
  for (int off=1; off<64; off<<=1){
    s1 += __shfl_xor(s1, off);
    s2 += __shfl_xor(s2, off);
  }
  const float m = s1 * (1.0f/DD);
  const float rstd = rsqrtf(s2*(1.0f/DD) - m*m + 1e-5f);
  const float4 g0 = *(const float4*)(gw + lane*8), g1 = *(const float4*)(gw + lane*8 + 4);
  const float4 b0 = *(const float4*)(bw + lane*8), b1 = *(const float4*)(bw + lane*8 + 4);
  float gg[8] = {g0.x,g0.y,g0.z,g0.w,g1.x,g1.y,g1.z,g1.w};
  float bb[8] = {b0.x,b0.y,b0.z,b0.w,b1.x,b1.y,b1.z,b1.w};
  short r[8];
  #pragma unroll
  for (int e=0;e<8;e++) r[e] = f2bf((xv[e]-m)*rstd*gg[e] + bb[e]);
  *(bf16x8*)&out[(size_t)row*DD + lane*8] = *(const bf16x8*)r;
}

// ---------------- weight transpose+cast ----------------
__global__ __launch_bounds__(256) void transpose_cast_kernel(const float* __restrict__ src,
    short* __restrict__ dst, int R, int C){
  __shared__ float tile[32][33];
  size_t off = (size_t)blockIdx.z * R * C;
  src += off; dst += off;
  int c0 = blockIdx.x*32, r0 = blockIdx.y*32;
  int tx = threadIdx.x & 31, ty = threadIdx.x >> 5;
  #pragma unroll
  for (int i=0;i<4;i++) tile[ty + i*8][tx] = src[(size_t)(r0+ty+i*8)*C + c0 + tx];
  __syncthreads();
  #pragma unroll
  for (int i=0;i<4;i++) dst[(size_t)(c0+ty+i*8)*R + r0 + tx] = f2bf(tile[tx][ty+i*8]);
}

// ---------------- plain cast f32 -> bf16 ----------------
__global__ void cast_kernel(const float* __restrict__ in, short* __restrict__ out, int n){
  for (int i = blockIdx.x*blockDim.x + threadIdx.x; i < n; i += gridDim.x*blockDim.x)
    out[i] = f2bf(in[i]);
}

// row-band XCD swizzle: XCD x owns row-tiles [x*gx/8, ...) x all col-tiles.
__device__ __forceinline__ void xcd_rowband(int gx, int gy, int& rowt, int& colt){
  int lin = blockIdx.y*gx + blockIdx.x;
  int x = lin & 7, j = lin >> 3;
  int jd = j / gy;
  rowt = x*(gx >> 3) + jd;
  colt = j - jd*gy;
}

// ---------------- GEMM, 128x128 tile, 8 waves (wave = 64x32), BK=32 DBUF (32KB), counted vmcnt ----------------
// EPI: 1 = +bias -> bf16; 2 = +bias,GELU -> bf16
template<int EPI>
__global__ __launch_bounds__(512) void gemm_dma(const short* __restrict__ A,
    const short* __restrict__ BT, const float* __restrict__ bias, void* __restrict__ C,
    int M, int N, int K)
{
  __shared__ short As[2][128*32];
  __shared__ short Bs[2][128*32];
  int rowt, colt;
  xcd_rowband(gridDim.x, gridDim.y, rowt, colt);
  const int row0 = rowt*128, col0 = colt*128;
  const int t = threadIdx.x, lane = t & 63, w = t >> 6;
  const int wm = w >> 2, wn = w & 3;
  const int rr = lane & 15, g = lane >> 4;
  f32x4 acc[4][2];
  #pragma unroll
  for (int m=0;m<4;m++)
    #pragma unroll
    for (int n=0;n<2;n++) acc[m][n] = (f32x4){0.f,0.f,0.f,0.f};

  const int srow = lane >> 2;
  const short* aP = A  + (size_t)(row0 + w*16 + srow)*K + (lane&3)*8;
  const short* bP = BT + (size_t)(col0 + w*16 + srow)*K + (lane&3)*8;

  const int nk = K >> 5;
  GL2LDS(aP, &As[0][w*512]);
  GL2LDS(bP, &Bs[0][w*512]);
  if (nk > 1){
    GL2LDS(aP + 32, &As[1][w*512]);
    GL2LDS(bP + 32, &Bs[1][w*512]);
  }
  for (int kt=0; kt<nk; kt++){
    if (kt < nk-1) asm volatile("s_waitcnt vmcnt(2)\n\ts_barrier" ::: "memory");
    else           asm volatile("s_waitcnt vmcnt(0)\n\ts_barrier" ::: "memory");
    const short* Ac = As[kt&1];
    const short* Bc = Bs[kt&1];
    bf16x8 af[4], bfr[2];
    #pragma unroll
    for (int m=0;m<4;m++) af[m]  = *(const bf16x8*)&Ac[(wm*64 + m*16 + rr)*32 + g*8];
    #pragma unroll
    for (int n=0;n<2;n++) bfr[n] = *(const bf16x8*)&Bc[(wn*32 + n*16 + rr)*32 + g*8];
    __builtin_amdgcn_s_setprio(1);
    #pragma unroll
    for (int m=0;m<4;m++)
      #pragma unroll
      for (int n=0;n<2;n++)
        acc[m][n] = __builtin_amdgcn_mfma_f32_16x16x32_bf16(af[m], bfr[n], acc[m][n], 0,0,0);
    __builtin_amdgcn_s_setprio(0);
    if (kt+2 < nk){
      asm volatile("s_waitcnt lgkmcnt(0)\n\ts_barrier" ::: "memory");
      const int ko = (kt+2) << 5;
      GL2LDS(aP + ko, &As[kt&1][w*512]);
      GL2LDS(bP + ko, &Bs[kt&1][w*512]);
    }
  }
  #pragma unroll
  for (int m=0;m<4;m++){
    #pragma unroll
    for (int n=0;n<2;n++){
      int cg = col0 + wn*32 + n*16 + rr;
      float bv = bias[cg];
      #pragma unroll
      for (int i=0;i<4;i++){
        int rg = row0 + wm*64 + m*16 + g*4 + i;
        float v = acc[m][n][i] + bv;
        size_t idx = (size_t)rg*N + cg;
        if constexpr (EPI==1) ((short*)C)[idx] = f2bf(v);
        else ((short*)C)[idx] = f2bf(gelu_f(v));
      }
    }
  }
}

// ---------------- GEMM, 256x128 tile, 8 waves (wave = 64x64, acc 4x4), BK=32 ring-of-3 ----------------
template<int EPI>
__global__ __launch_bounds__(512) void gemm_dma_256(const short* __restrict__ A,
    const short* __restrict__ BT, const float* __restrict__ bias, void* __restrict__ C,
    int M, int N, int K)
{
  __shared__ short As[3][256*32];   // 48 KB
  __shared__ short Bs[3][128*32];   // 24 KB
  int rowt, colt;
  xcd_rowband(gridDim.x, gridDim.y, rowt, colt);
  const int row0 = rowt*256, col0 = colt*128;
  const int t = threadIdx.x, lane = t & 63, w = t >> 6;
  const int wm = w >> 1, wn = w & 1;
  const int rr = lane & 15, g = lane >> 4;
  f32x4 acc[4][4];
  #pragma unroll
  for (int m=0;m<4;m++)
    #pragma unroll
    for (int n=0;n<4;n++) acc[m][n] = (f32x4){0.f,0.f,0.f,0.f};

  const int srow = lane >> 2;
  const short* aP = A  + (size_t)(row0 + w*32 + srow)*K + (lane&3)*8;
  const short* bP = BT + (size_t)(col0 + w*16 + srow)*K + (lane&3)*8;

  const int nk = K >> 5;
  #pragma unroll
  for (int i=0;i<2;i++) GL2LDS(aP + (size_t)i*16*K, &As[0][w*1024 + i*512]);
  GL2LDS(bP, &Bs[0][w*512]);
  if (nk > 1){
    #pragma unroll
    for (int i=0;i<2;i++) GL2LDS(aP + (size_t)i*16*K + 32, &As[1][w*1024 + i*512]);
    GL2LDS(bP + 32, &Bs[1][w*512]);
  }
  int cur = 0, st = 2;
  for (int kt=0; kt<nk; kt++){
    if (kt < nk-1) asm volatile("s_waitcnt vmcnt(3) lgkmcnt(0)\n\ts_barrier" ::: "memory");
    else           asm volatile("s_waitcnt vmcnt(0) lgkmcnt(0)\n\ts_barrier" ::: "memory");
    if (kt+2 < nk){
      const int ko = (kt+2) << 5;
      #pragma unroll
      for (int i=0;i<2;i++) GL2LDS(aP + (size_t)i*16*K + ko, &As[st][w*1024 + i*512]);
      GL2LDS(bP + ko, &Bs[st][w*512]);
    }
    const short* Ac = As[cur];
    const short* Bc = Bs[cur];
    bf16x8 af[4], bfr[4];
    #pragma unroll
    for (int m=0;m<4;m++) af[m]  = *(const bf16x8*)&Ac[(wm*64 + m*16 + rr)*32 + g*8];
    #pragma unroll
    for (int n=0;n<4;n++) bfr[n] = *(const bf16x8*)&Bc[(wn*64 + n*16 + rr)*32 + g*8];
    __builtin_amdgcn_s_setprio(1);
    #pragma unroll
    for (int m=0;m<4;m++)
      #pragma unroll
      for (int n=0;n<4;n++)
        acc[m][n] = __builtin_amdgcn_mfma_f32_16x16x32_bf16(af[m], bfr[n], acc[m][n], 0,0,0);
    __builtin_amdgcn_s_setprio(0);
    cur = (cur==2) ? 0 : cur+1;
    st  = (st==2)  ? 0 : st+1;
  }
  #pragma unroll
  for (int m=0;m<4;m++){
    #pragma unroll
    for (int n=0;n<4;n++){
      int cg = col0 + wn*64 + n*16 + rr;
      float bv = bias[cg];
      #pragma unroll
      for (int i=0;i<4;i++){
        int rg = row0 + wm*64 + m*16 + g*4 + i;
        float v = acc[m][n][i] + bv;
        size_t idx = (size_t)rg*N + cg;
        if constexpr (EPI==1) ((short*)C)[idx] = f2bf(v);
        else ((short*)C)[idx] = f2bf(gelu_f(v));
      }
    }
  }
}

// ---------------- GEMM 128x64 tile, 8 waves (wave = 32x32), BK=32 ring-of-3, residual += ----------------
__global__ __launch_bounds__(512) void gemm_dma_n64(const short* __restrict__ A,
    const short* __restrict__ BT, const float* __restrict__ bias, float* __restrict__ C,
    int M, int N, int K)
{
  __shared__ short As[3][128*32];
  __shared__ short Bs[3][64*32];
  int rowt, colt;
  xcd_rowband(gridDim.x, gridDim.y, rowt, colt);
  const int row0 = rowt*128, col0 = colt*64;
  const int t = threadIdx.x, lane = t & 63, w = t >> 6;
  const int wm = w >> 1, wn = w & 1;
  const int rr = lane & 15, g = lane >> 4;
  f32x4 acc[2][2];
  #pragma unroll
  for (int m=0;m<2;m++)
    #pragma unroll
    for (int n=0;n<2;n++) acc[m][n] = (f32x4){0.f,0.f,0.f,0.f};

  const int srow = lane >> 2;
  const short* aP = A  + (size_t)(row0 + w*16 + srow)*K + (lane&3)*8;
  const short* bP = BT + (size_t)(col0 + (w&3)*16 + srow)*K + (lane&3)*8;

  const int nk = K >> 5;
  GL2LDS(aP, &As[0][w*512]);
  if (w < 4) GL2LDS(bP, &Bs[0][w*512]);
  if (nk > 1){
    GL2LDS(aP + 32, &As[1][w*512]);
    if (w < 4) GL2LDS(bP + 32, &Bs[1][w*512]);
  }
  int cur = 0, st = 2;
  for (int kt=0; kt<nk; kt++){
    if (kt < nk-1){
      if (w < 4) asm volatile("s_waitcnt vmcnt(2) lgkmcnt(0)\n\ts_barrier" ::: "memory");
      else       asm volatile("s_waitcnt vmcnt(1) lgkmcnt(0)\n\ts_barrier" ::: "memory");
    } else       asm volatile("s_waitcnt vmcnt(0) lgkmcnt(0)\n\ts_barrier" ::: "memory");
    if (kt+2 < nk){
      const int ko = (kt+2) << 5;
      GL2LDS(aP + ko, &As[st][w*512]);
      if (w < 4) GL2LDS(bP + ko, &Bs[st][w*512]);
    }
    const short* Ac = As[cur];
    const short* Bc = Bs[cur];
    bf16x8 af[2], bfr[2];
    #pragma unroll
    for (int m=0;m<2;m++) af[m]  = *(const bf16x8*)&Ac[(wm*32 + m*16 + rr)*32 + g*8];
    #pragma unroll
    for (int n=0;n<2;n++) bfr[n] = *(const bf16x8*)&Bc[(wn*32 + n*16 + rr)*32 + g*8];
    __builtin_amdgcn_s_setprio(1);
    #pragma unroll
    for (int m=0;m<2;m++)
      #pragma unroll
      for (int n=0;n<2;n++)
        acc[m][n] = __builtin_amdgcn_mfma_f32_16x16x32_bf16(af[m], bfr[n], acc[m][n], 0,0,0);
    __builtin_amdgcn_s_setprio(0);
    cur = (cur==2) ? 0 : cur+1;
    st  = (st==2)  ? 0 : st+1;
  }
  #pragma unroll
  for (int m=0;m<2;m++){
    #pragma unroll
    for (int n=0;n<2;n++){
      int cg = col0 + wn*32 + n*16 + rr;
      float bv = bias[cg];
      #pragma unroll
      for (int i=0;i<4;i++){
        int rg = row0 + wm*32 + m*16 + g*4 + i;
        C[(size_t)rg*N + cg] += acc[m][n][i] + bv;
      }
    }
  }
}

// ---------------- small reg-staged GEMM (lm_head) ----------------
template<int BM, int BN>
__global__ __launch_bounds__(256) void gemm_small(const short* __restrict__ A,
    const short* __restrict__ BT, float* __restrict__ C, int M, int N, int K)
{
  constexpr int FM = BM/32, FN = BN/32;
  __shared__ short As[BM][72];
  __shared__ short Bs[BN][72];
  const int row0 = blockIdx.x*BM, col0 = blockIdx.y*BN;
  const int t = threadIdx.x, lane = t & 63, w = t >> 6;
  const int wm = w >> 1, wn = w & 1;
  const int rr = lane & 15, kg = (lane >> 4)*8;
  f32x4 acc[FM][FN];
  #pragma unroll
  for (int m=0;m<FM;m++)
    #pragma unroll
    for (int n=0;n<FN;n++) acc[m][n] = (f32x4){0.f,0.f,0.f,0.f};

  for (int kt=0; kt<K; kt+=64){
    #pragma unroll
    for (int i=0;i<BM/32;i++){
      int cid = t + i*256; int r = cid >> 3; int c = (cid & 7)*8;
      *(bf16x8*)&As[r][c] = *(const bf16x8*)&A[(size_t)(row0+r)*K + kt + c];
    }
    #pragma unroll
    for (int i=0;i<BN/32;i++){
      int cid = t + i*256; int r = cid >> 3; int c = (cid & 7)*8;
      *(bf16x8*)&Bs[r][c] = *(const bf16x8*)&BT[(size_t)(col0+r)*K + kt + c];
    }
    __syncthreads();
    #pragma unroll
    for (int ks=0; ks<2; ks++){
      bf16x8 af[FM], bfr[FN];
      #pragma unroll
      for (int m=0;m<FM;m++) af[m] = *(const bf16x8*)&As[wm*FM*16 + m*16 + rr][ks*32 + kg];
      #pragma unroll
      for (int n=0;n<FN;n++) bfr[n] = *(const bf16x8*)&Bs[wn*FN*16 + n*16 + rr][ks*32 + kg];
      #pragma unroll
      for (int m=0;m<FM;m++)
        #pragma unroll
        for (int n=0;n<FN;n++)
          acc[m][n] = __builtin_amdgcn_mfma_f32_16x16x32_bf16(af[m], bfr[n], acc[m][n], 0,0,0);
    }
    __syncthreads();
  }
  #pragma unroll
  for (int m=0;m<FM;m++)
    #pragma unroll
    for (int n=0;n<FN;n++){
      int cg = col0 + wn*FN*16 + n*16 + rr;
      #pragma unroll
      for (int i=0;i<4;i++){
        int rg = row0 + wm*FM*16 + m*16 + (lane>>4)*4 + i;
        C[(size_t)rg*N + cg] = acc[m][n][i];
      }
    }
}

// ---------------- attention: per-tile compute for one q-state ----------------
__device__ __forceinline__ void attn_tile(const short* __restrict__ Kc,
    const short* __restrict__ Vc, const bf16x8* qr, f32x4* oacc,
    float& mrun, float& lpart, int qi, int g, int qloc, bool diag)
{
  f32x4 sacc[4];
  #pragma unroll
  for (int f=0; f<4; f++) sacc[f] = (f32x4){0.f,0.f,0.f,0.f};
  __builtin_amdgcn_s_setprio(1);
  #pragma unroll
  for (int ks=0; ks<2; ks++){
    #pragma unroll
    for (int f=0; f<4; f++){
      bf16x8 kf = *(const bf16x8*)&Kc[(f*16 + qi)*64 + (((ks*4 + g) ^ (qi&7))*8)];
      sacc[f] = __builtin_amdgcn_mfma_f32_16x16x32_bf16(kf, qr[ks], sacc[f], 0,0,0);
    }
  }
  __builtin_amdgcn_s_setprio(0);

  float p[4][4];
  if (diag){
    #pragma unroll
    for (int f=0; f<4; f++)
      #pragma unroll
      for (int i=0; i<4; i++){
        int koffs = f*16 + g*4 + i;
        p[f][i] = (koffs <= qloc) ? sacc[f][i] : -1e30f;
      }
  } else {
    #pragma unroll
    for (int f=0; f<4; f++)
      #pragma unroll
      for (int i=0; i<4; i++) p[f][i] = sacc[f][i];
  }
  float t0 = fmaxf(fmaxf(p[0][0],p[0][1]), fmaxf(p[0][2],p[0][3]));
  float t1 = fmaxf(fmaxf(p[1][0],p[1][1]), fmaxf(p[1][2],p[1][3]));
  float t2 = fmaxf(fmaxf(p[2][0],p[2][1]), fmaxf(p[2][2],p[2][3]));
  float t3 = fmaxf(fmaxf(p[3][0],p[3][1]), fmaxf(p[3][2],p[3][3]));
  float tm = fmaxf(fmaxf(t0,t1), fmaxf(t2,t3));
  tm = fmaxf(tm, __shfl_xor(tm, 16));
  tm = xmax32(tm);
  if (!__all(tm <= mrun + 8.f)){            // defer-max (log2 units)
    float mnew = fmaxf(mrun, tm);
    float corr = ex2(mrun - mnew);
    lpart *= corr;
    #pragma unroll
    for (int mf=0; mf<4; mf++)
      #pragma unroll
      for (int i=0; i<4; i++) oacc[mf][i] *= corr;
    mrun = mnew;
  }
  float ts = 0.f;
  #pragma unroll
  for (int f=0; f<4; f++)
    #pragma unroll
    for (int i=0; i<4; i++){
      float e = ex2(p[f][i] - mrun);
      p[f][i] = e;
      ts += e;
    }
  lpart += ts;

  __builtin_amdgcn_s_setprio(1);
  #pragma unroll
  for (int w2=0; w2<2; w2++){
    union { unsigned u[4]; bf16x8 v; } bfr;
    bfr.u[0] = cvtpk(p[2*w2  ][0], p[2*w2  ][1]);
    bfr.u[1] = cvtpk(p[2*w2  ][2], p[2*w2  ][3]);
    bfr.u[2] = cvtpk(p[2*w2+1][0], p[2*w2+1][1]);
    bfr.u[3] = cvtpk(p[2*w2+1][2], p[2*w2+1][3]);
    #pragma unroll
    for (int mf=0; mf<4; mf++){
      const short* vp = &Vc[(mf*16 + qi)*72 + w2*32 + g*4];
      union { bf16x4 h[2]; bf16x8 v; } af;
      af.h[0] = *(const bf16x4*)vp;
      af.h[1] = *(const bf16x4*)(vp + 16);
      oacc[mf] = __builtin_amdgcn_mfma_f32_16x16x32_bf16(af.v, bfr.v, oacc[mf], 0,0,0);
    }
  }
  __builtin_amdgcn_s_setprio(0);
}

// ---------------- MFMA flash attention v8: 128 q-rows/block, 8 waves ----------------
// 512 blocks (2/CU), 16 waves/CU. Waves 4-7 own K-DMA, waves 0-3 own V load+pack.
__global__ __launch_bounds__(512) void attn_kernel(const short* __restrict__ qkv, short* __restrict__ o){
  __shared__ __align__(16) char smem[34816];
  short* KsB = (short*)smem;             // 2 x [64][64], chunk-swizzled
  short* VtB = (short*)(smem + 16384);   // 2 x Vt[d][k] [64][72]
  float* Osh = (float*)smem;             // [128][65] alias (epilogue only)

  const int lin = blockIdx.x;            // 512 blocks
  const int xcd = lin & 7, idx = lin >> 3;
  const int bh = xcd*4 + (idx & 3);
  const int j = 15 - (idx >> 2);         // heavy first
  const int q0 = j*128;
  const int nt = 2*j + 2;
  const int b = bh >> 3, hh = bh & 7;

  const int t = threadIdx.x, lane = t & 63, wid = t >> 6;   // 8 waves
  const int g = lane >> 4, qi = lane & 15;
  const int qg = q0 + wid*16 + qi;       // global q row
  const int myqt = 2*j + (wid >> 2);     // this wave's q-tile index
  const int qrel = ((wid & 3) << 4) + qi;
  const size_t base = (size_t)b*TT*3*DD + hh*64;

  bf16x8 qreg[2];
  {
    const float qs = 0.125f * 1.44269504f;
    const short* qp = qkv + base + (size_t)qg*3*DD + g*8;
    qreg[0] = *(const bf16x8*)&qp[0];
    qreg[1] = *(const bf16x8*)&qp[32];
    #pragma unroll
    for (int jj=0;jj<8;jj++){
      qreg[0][jj] = f2bf(qs * bf2f(qreg[0][jj]));
      qreg[1][jj] = f2bf(qs * bf2f(qreg[1][jj]));
    }
  }
  f32x4 oacc[4];
  #pragma unroll
  for (int mf=0; mf<4; mf++) oacc[mf] = (f32x4){0.f,0.f,0.f,0.f};
  float mrun = -1e30f, lrun = 0.f;

  const int kw = wid & 3;
  const short* ksrc = qkv + base + DD + (size_t)(kw*16 + (lane>>3))*3*DD
                      + (((lane&7) ^ (lane>>3))*8);
  const int vk = (t & 31)*2, vd = ((t >> 5) & 7)*8;
  const short* vsrc = qkv + base + 2*DD + (size_t)vk*3*DD + vd;

  // ---- prologue: K(0) DMA (hi waves), V(0)+V(1) regs (lo waves), write Vt(0) ----
  bf16x8 v0a, v0b, vLoA, vLoB;
  if (wid >= 4){
    GL2LDS(ksrc, KsB + kw*1024);
    GL2LDS(ksrc + (size_t)8*3*DD, KsB + kw*1024 + 512);
  } else {
    v0a = *(const bf16x8*)vsrc;
    v0b = *(const bf16x8*)(vsrc + 3*DD);
    vLoA = *(const bf16x8*)(vsrc + (size_t)64*3*DD);
    vLoB = *(const bf16x8*)(vsrc + (size_t)64*3*DD + 3*DD);
  }
  asm volatile("s_waitcnt vmcnt(0)" ::: "memory");
  if (wid < 4){
    #pragma unroll
    for (int e=0;e<8;e++)
      *(unsigned*)&VtB[(vd+e)*72 + vk] =
          (unsigned)(unsigned short)v0a[e] | ((unsigned)(unsigned short)v0b[e] << 16);
  }

  for (int kb = 0; kb < nt; kb++){
    asm volatile("s_waitcnt vmcnt(0) lgkmcnt(0)\n\ts_barrier" ::: "memory");
    bf16x8 vHiA = vLoA, vHiB = vLoB;
    if (kb+1 < nt){
      const size_t koff = (size_t)(kb+1)*64*3*DD;
      if (wid >= 4){
        short* kd = KsB + ((kb+1)&1)*4096 + kw*1024;
        GL2LDS(ksrc + koff, kd);
        GL2LDS(ksrc + koff + (size_t)8*3*DD, kd + 512);
      } else {
        short* Vn = VtB + ((kb+1)&1)*4608;
        #pragma unroll
        for (int e=0;e<8;e++)
          *(unsigned*)&Vn[(vd+e)*72 + vk] =
              (unsigned)(unsigned short)vLoA[e] | ((unsigned)(unsigned short)vLoB[e] << 16);
      }
    }
    if (kb+2 < nt && wid < 4){
      const size_t koff2 = (size_t)(kb+2)*64*3*DD;
      vHiA = *(const bf16x8*)(vsrc + koff2);
      vHiB = *(const bf16x8*)(vsrc + koff2 + 3*DD);
    }
    const short* Kc = KsB + (kb&1)*4096;
    const short* Vc = VtB + (kb&1)*4608;

    if (kb <= myqt)
      attn_tile(Kc, Vc, qreg, oacc, mrun, lrun, qi, g, qrel, kb == myqt);

    vLoA = vHiA; vLoB = vHiB;
  }

  lrun += __shfl_xor(lrun, 16);
  lrun = xadd32(lrun);

  // epilogue: O^T frags -> Osh[128][65] -> coalesced bf16 store
  __syncthreads();
  const float inv = 1.f / lrun;
  const int qloc128 = wid*16 + qi;
  #pragma unroll
  for (int mf=0; mf<4; mf++)
    #pragma unroll
    for (int i=0; i<4; i++)
      Osh[qloc128*65 + mf*16 + g*4 + i] = oacc[mf][i] * inv;
  __syncthreads();
  {
    const int orow = t >> 2, cc = (t & 3) * 16;
    short tmp[16];
    #pragma unroll
    for (int e=0; e<16; e++) tmp[e] = f2bf(Osh[orow*65 + cc + e]);
    short* op = o + ((size_t)b*TT + q0 + orow)*DD + hh*64 + cc;
    *(bf16x8*)&op[0] = *(const bf16x8*)&tmp[0];
    *(bf16x8*)&op[8] = *(const bf16x8*)&tmp[8];
  }
}

extern "C" void kernel_launch(void* const* d_in, const int* in_sizes, int n_in,
                              void* d_out, int out_size, void* d_ws, size_t ws_size,
                              hipStream_t stream) {
  const int*   x      = (const int*)d_in[0];
  const float* tok    = (const float*)d_in[1];
  const float* pos    = (const float*)d_in[2];
  const float* attn_w = (const float*)d_in[3];
  const float* attn_b = (const float*)d_in[4];
  const float* proj_w = (const float*)d_in[5];
  const float* proj_b = (const float*)d_in[6];
  const float* ln1_g  = (const float*)d_in[7];
  const float* ln1_b  = (const float*)d_in[8];
  const float* ln2_g  = (const float*)d_in[9];
  const float* ln2_b  = (const float*)d_in[10];
  const float* ff1_w  = (const float*)d_in[11];
  const float* ff1_b  = (const float*)d_in[12];
  const float* ff2_w  = (const float*)d_in[13];
  const float* ff2_b  = (const float*)d_in[14];
  const float* lnf_g  = (const float*)d_in[15];
  const float* lnf_b  = (const float*)d_in[16];

  char* p = (char*)d_ws;
  float* h   = (float*)p; p += (size_t)ROWS*DD*4;
  short* hn  = (short*)p; p += (size_t)ROWS*DD*2;
  short* qkv = (short*)p; p += (size_t)ROWS*3*DD*2;
  short* ob  = (short*)p; p += (size_t)ROWS*DD*2;
  short* ffb = (short*)p; p += (size_t)ROWS*FFD*2;
  short* awT = (short*)p; p += (size_t)LL*3*DD*DD*2;
  short* pwT = (short*)p; p += (size_t)LL*DD*DD*2;
  short* f1T = (short*)p; p += (size_t)LL*FFD*DD*2;
  short* f2T = (short*)p; p += (size_t)LL*DD*FFD*2;
  short* lmT = (short*)p; p += (size_t)VV*DD*2;

  transpose_cast_kernel<<<dim3(48,16,8),256,0,stream>>>(attn_w, awT, DD, 3*DD);
  transpose_cast_kernel<<<dim3(16,16,8),256,0,stream>>>(proj_w, pwT, DD, DD);
  transpose_cast_kernel<<<dim3(64,16,8),256,0,stream>>>(ff1_w, f1T, DD, FFD);
  transpose_cast_kernel<<<dim3(16,64,8),256,0,stream>>>(ff2_w, f2T, FFD, DD);
  cast_kernel<<<128,256,0,stream>>>(tok, lmT, VV*DD);
  embed_kernel<<<ROWS,128,0,stream>>>(x, tok, pos, h);

  for (int l=0;l<LL;l++){
    ln_kernel<<<ROWS/4,256,0,stream>>>(h, ln1_g + l*DD, ln1_b + l*DD, hn);
    gemm_dma<1><<<dim3(ROWS/128, (3*DD)/128),512,0,stream>>>(
        hn, awT + (size_t)l*3*DD*DD, attn_b + (size_t)l*3*DD, qkv, ROWS, 3*DD, DD);
    attn_kernel<<<512,512,0,stream>>>(qkv, ob);
    gemm_dma_n64<<<dim3(ROWS/128, DD/64),512,0,stream>>>(
        ob, pwT + (size_t)l*DD*DD, proj_b + (size_t)l*DD, h, ROWS, DD, DD);
    ln_kernel<<<ROWS/4,256,0,stream>>>(h, ln2_g + l*DD, ln2_b + l*DD, hn);
    gemm_dma_256<2><<<dim3(ROWS/256, FFD/128),512,0,stream>>>(
        hn, f1T + (size_t)l*FFD*DD, ff1_b + (size_t)l*FFD, ffb, ROWS, FFD, DD);
    gemm_dma_n64<<<dim3(ROWS/128, DD/64),512,0,stream>>>(
        ffb, f2T + (size_t)l*DD*FFD, ff2_b + (size_t)l*DD, h, ROWS, DD, FFD);
  }
  ln_kernel<<<ROWS/4,256,0,stream>>>(h, lnf_g, lnf_b, hn);
  gemm_small<64,64><<<dim3(ROWS/64, VV/64),256,0,stream>>>(
      hn, lmT, (float*)d_out, ROWS, VV, DD);
}